// Round 2
// baseline (233.957 us; speedup 1.0000x reference)
//
#include <hip/hip_runtime.h>

// Leaky LIF SNN forward:
//   reset_t = H(mem_{t-1} - 1)
//   mem_t   = 0.5*mem_{t-1} + x_t - reset_t
//   spk_t   = H(mem_t - 1)
// x, spk: [T=128, B=64, N=4096] fp32.
//
// R1 post-mortem: float4/thread -> only 1 wave/SIMD (9% occupancy), 2.4 TB/s.
// R2: scalar float/thread -> 4 waves/SIMD; software-pipelined prefetch so the
// load-wait never drains pending spike stores; nontemporal spike stores.

#define T_STEPS 128
#define U 16   // timesteps per pipeline batch; 16 loads in flight per wave

__global__ __launch_bounds__(256) void snn_leaky_fwd(const float* __restrict__ x,
                                                     float* __restrict__ out,
                                                     int n) {
    const int idx = blockIdx.x * blockDim.x + threadIdx.x;
    if (idx >= n) return;

    const float* xp = x + idx;
    float* op = out + idx;

    float mem = 0.0f;
    float cur[U], nxt[U];

    // prologue: batch 0 in flight
#pragma unroll
    for (int u = 0; u < U; ++u) cur[u] = xp[(size_t)u * n];

    for (int t = 0; t < T_STEPS - U; t += U) {
        // prefetch batch t+U first — these 16 loads are the only thing the
        // upcoming compute has to wait behind
#pragma unroll
        for (int u = 0; u < U; ++u) nxt[u] = xp[(size_t)(t + U + u) * n];
        // compute + store batch t (stores are fire-and-forget, nontemporal)
#pragma unroll
        for (int u = 0; u < U; ++u) {
            mem = 0.5f * mem + cur[u] - (mem > 1.0f ? 1.0f : 0.0f);
            float spk = (mem > 1.0f) ? 1.0f : 0.0f;
            __builtin_nontemporal_store(spk, op + (size_t)(t + u) * n);
        }
#pragma unroll
        for (int u = 0; u < U; ++u) cur[u] = nxt[u];
    }

    // epilogue: last batch
#pragma unroll
    for (int u = 0; u < U; ++u) {
        mem = 0.5f * mem + cur[u] - (mem > 1.0f ? 1.0f : 0.0f);
        float spk = (mem > 1.0f) ? 1.0f : 0.0f;
        __builtin_nontemporal_store(spk, op + (size_t)(T_STEPS - U + u) * n);
    }
}

extern "C" void kernel_launch(void* const* d_in, const int* in_sizes, int n_in,
                              void* d_out, int out_size, void* d_ws, size_t ws_size,
                              hipStream_t stream) {
    const float* x = (const float*)d_in[0];
    float* out = (float*)d_out;

    const int total = in_sizes[0];          // T*B*N = 128*64*4096
    const int n = total / T_STEPS;          // B*N   = 262144 neurons

    const int block = 256;
    const int grid = (n + block - 1) / block;   // 1024 blocks -> 16 waves/CU
    snn_leaky_fwd<<<grid, block, 0, stream>>>(x, out, n);
}

// Round 3
// 233.826 us; speedup vs baseline: 1.0006x; 1.0006x over previous
//
#include <hip/hip_runtime.h>

// Leaky LIF SNN forward:
//   reset_t = H(mem_{t-1} - 1)
//   mem_t   = 0.5*mem_{t-1} + x_t - reset_t
//   spk_t   = H(mem_t - 1)
// x, spk: [T=128, B=64, N=4096] fp32.
//
// R1/R2 post-mortem: both kernels batch-issued loads then DRAINED the whole
// batch before the next issue (R2's cur=nxt copy forced waiting on the loads
// issued that same iteration). Bursty issue -> 2.45 TB/s in both despite 4x
// occupancy difference.
// R3: continuous rolling register ring, full T-unroll. Each step waits for
// exactly ONE load (fine-grained vmcnt), re-issues that slot, computes,
// nt-stores. Load pipe never drains.

#define T_STEPS 128
#define D 24   // prefetch distance (register ring depth)

__global__ __launch_bounds__(256) void snn_leaky_fwd(const float* __restrict__ x,
                                                     float* __restrict__ out,
                                                     int n) {
    const int idx = blockIdx.x * blockDim.x + threadIdx.x;
    if (idx >= n) return;

    const float* xp = x + idx;
    float* op = out + idx;

    float buf[D];
    float mem = 0.0f;

    // prologue: fill the ring
#pragma unroll
    for (int u = 0; u < D; ++u) buf[u] = xp[(size_t)u * n];

    // steady state: one consume + one issue per step, fully unrolled so the
    // ring lives in registers and waits are per-slot fine-grained vmcnt.
#pragma unroll
    for (int t = 0; t < T_STEPS; ++t) {
        const float v = buf[t % D];                       // waits for load t only
        if (t + D < T_STEPS) {
            buf[t % D] = xp[(size_t)(t + D) * n];         // refill slot immediately
        }
        mem = 0.5f * mem + v - (mem > 1.0f ? 1.0f : 0.0f);
        const float spk = (mem > 1.0f) ? 1.0f : 0.0f;
        __builtin_nontemporal_store(spk, op + (size_t)t * n);
    }
}

extern "C" void kernel_launch(void* const* d_in, const int* in_sizes, int n_in,
                              void* d_out, int out_size, void* d_ws, size_t ws_size,
                              hipStream_t stream) {
    const float* x = (const float*)d_in[0];
    float* out = (float*)d_out;

    const int total = in_sizes[0];          // T*B*N = 128*64*4096
    const int n = total / T_STEPS;          // B*N   = 262144 neurons

    const int block = 256;
    const int grid = (n + block - 1) / block;   // 1024 blocks -> 16 waves/CU
    snn_leaky_fwd<<<grid, block, 0, stream>>>(x, out, n);
}

// Round 4
// 226.166 us; speedup vs baseline: 1.0344x; 1.0339x over previous
//
#include <hip/hip_runtime.h>

// Leaky LIF SNN forward, x/spk: [T=128, B*N=262144] fp32.
//   reset_t = H(mem_{t-1} - 1); mem_t = 0.5*mem_{t-1} + x_t - reset_t; spk_t = H(mem_t - 1)
//
// R1-R3: 2.45 TB/s invariant across {float4/scalar} x {4/16 waves/CU} x
// {bursty/rolling} -> DRAM page-activate bound (stride 2^20: row bits flip
// every visit, <=1KB visits). R4: T-split into 2 phases with exact warmup
// recompute -> 1KB float4 visits AND 8 waves/CU simultaneously (previously
// excluded by waves*chunk = 1MB/row budget). Redundant reads land in the
// shared per-XCD L2 (phase bit placed so both phases of a chunk hit the same
// XCD under round-robin) / L3. Normal stores so L2 aggregates write-back.

#define T_STEPS 128
#define T_HALF 64
#define D 8   // rolling ring depth (float4 rows in flight per wave: 8 KB)

__device__ __forceinline__ float4 lif_step(float4& mem, const float4 v) {
    mem.x = 0.5f * mem.x + v.x - (mem.x > 1.0f ? 1.0f : 0.0f);
    mem.y = 0.5f * mem.y + v.y - (mem.y > 1.0f ? 1.0f : 0.0f);
    mem.z = 0.5f * mem.z + v.z - (mem.z > 1.0f ? 1.0f : 0.0f);
    mem.w = 0.5f * mem.w + v.w - (mem.w > 1.0f ? 1.0f : 0.0f);
    float4 s;
    s.x = mem.x > 1.0f ? 1.0f : 0.0f;
    s.y = mem.y > 1.0f ? 1.0f : 0.0f;
    s.z = mem.z > 1.0f ? 1.0f : 0.0f;
    s.w = mem.w > 1.0f ? 1.0f : 0.0f;
    return s;
}

__global__ __launch_bounds__(256) void snn_leaky_fwd(const float4* __restrict__ x,
                                                     float4* __restrict__ out,
                                                     int n4) {
    // phase in the HIGH bit: blocks c and 256+c land on the same XCD (b%8
    // equal) so phase1's warmup reads hit the L2 lines phase0 just pulled.
    const int chunk = blockIdx.x & 255;
    const int phase = blockIdx.x >> 8;
    const int col = chunk * 256 + threadIdx.x;   // float4 column index

    const float4* xp = x + col;
    float4* op = out + col;

    float4 buf[D];
    float4 mem = make_float4(0.f, 0.f, 0.f, 0.f);

#pragma unroll
    for (int u = 0; u < D; ++u) buf[u] = xp[(size_t)u * n4];

    if (phase == 0) {
#pragma unroll
        for (int t = 0; t < T_HALF; ++t) {
            const float4 v = buf[t % D];
            if (t + D < T_HALF) buf[t % D] = xp[(size_t)(t + D) * n4];
            const float4 s = lif_step(mem, v);
            op[(size_t)t * n4] = s;
        }
    } else {
        // warmup: bitwise-identical mem recurrence for t in [0,64), no stores
#pragma unroll
        for (int t = 0; t < T_HALF; ++t) {
            const float4 v = buf[t % D];
            buf[t % D] = xp[(size_t)(t + D) * n4];   // t+D < 128 always here
            (void)lif_step(mem, v);
        }
#pragma unroll
        for (int t = T_HALF; t < T_STEPS; ++t) {
            const float4 v = buf[t % D];
            if (t + D < T_STEPS) buf[t % D] = xp[(size_t)(t + D) * n4];
            const float4 s = lif_step(mem, v);
            op[(size_t)t * n4] = s;
        }
    }
}

extern "C" void kernel_launch(void* const* d_in, const int* in_sizes, int n_in,
                              void* d_out, int out_size, void* d_ws, size_t ws_size,
                              hipStream_t stream) {
    const float4* x = (const float4*)d_in[0];
    float4* out = (float4*)d_out;

    const int total = in_sizes[0];            // T*B*N = 128*64*4096
    const int n4 = total / T_STEPS / 4;       // 65536 float4 columns

    // 256 column chunks x 2 phases = 512 blocks -> 2 blocks/CU, 8 waves/CU,
    // 1 KB contiguous per wave per row visit.
    snn_leaky_fwd<<<512, 256, 0, stream>>>(x, out, n4);
}